// Round 2
// baseline (132.116 us; speedup 1.0000x reference)
//
#include <hip/hip_runtime.h>

// VQ-VAE VectorQuantizer for MI355X.
// inputs: d_in[0] = inputs [64, 64, 32, 32] fp32 (NCHW), d_in[1] = emb_w [512, 64] fp32
// output d_out (fp32): [loss(1), quantized NCHW (64*64*32*32), idx (65536)]
//
// Correctness note: the reference computes dist = ||x||^2 + ||e||^2 - 2 x.e in fp32,
// where ||x||^2 ~ 64 quantizes dist to a ~7.6e-6 grid; ~100/65536 points have quantized
// TIES that argmin resolves by first index. We bit-replicate that arithmetic
// (numpy pairwise-sum order for the norms, fp32 rounding sequence for dist) and
// tie-break by smallest index.

#define D_    64
#define HW_   1024
#define N_    65536
#define K_    512
#define M_    128    // points per block
#define CH_   128    // codes per chunk
#define NCH_  4
#define NDTOT (N_ * D_)

// ||e_k||^2 in numpy pairwise-summation order (n=64: 8 accumulators, tree combine)
__global__ __launch_bounds__(256) void vq_norm_kernel(const float* __restrict__ emb,
                                                      float* __restrict__ wsn) {
    int k = blockIdx.x * 256 + threadIdx.x;
    if (k < K_) {
        const float* e = emb + k * D_;
        float r[8];
#pragma unroll
        for (int j = 0; j < 8; ++j) r[j] = __fmul_rn(e[j], e[j]);
#pragma unroll
        for (int i = 1; i < 8; ++i)
#pragma unroll
            for (int j = 0; j < 8; ++j)
                r[j] = __fadd_rn(r[j], __fmul_rn(e[i * 8 + j], e[i * 8 + j]));
        float s = __fadd_rn(__fadd_rn(__fadd_rn(r[0], r[1]), __fadd_rn(r[2], r[3])),
                            __fadd_rn(__fadd_rn(r[4], r[5]), __fadd_rn(r[6], r[7])));
        wsn[k] = s;
    }
}

__global__ __launch_bounds__(256, 2) void vq_main_kernel(const float* __restrict__ inp,
                                                         const float* __restrict__ emb,
                                                         const float* __restrict__ wsn,
                                                         float* __restrict__ out) {
    __shared__ float lds[16520];
    float* ldsx = lds;                  // xT[d][p]   : 64 x 128 (persists)
    float* ldse = lds + 8192;           // embT[d][k] : 64 x 128 chunk, later reduce scratch
    float* sxs  = lds + 16384;          // ||x_p||^2  : 128
    float* partial = lds + 16512;       // 4 loss partials

    const int tid = threadIdx.x;
    const int pg  = tid & 15;           // 16 point-groups of 8
    const int kg  = tid >> 4;           // 16 code-groups of 8
    const int n0  = blockIdx.x * M_;
    const int b   = n0 >> 10;
    const int hw0 = n0 & 1023;
    const float* xbase = inp + b * (D_ * HW_) + hw0;

    // ---- stage xT[d][p] (coalesced: 128 consecutive floats per d) ----
#pragma unroll
    for (int i = 0; i < 8; ++i) {
        int q  = i * 256 + tid;         // 0..2047 = 64 d * 32 quads
        int d  = q >> 5;
        int pq = q & 31;
        float4 v = *(const float4*)(xbase + d * HW_ + pq * 4);
        *(float4*)(ldsx + d * M_ + pq * 4) = v;
    }
    __syncthreads();

    // ---- sxs[p] = ||x_p||^2, numpy pairwise order ----
    if (tid < M_) {
        float r[8];
#pragma unroll
        for (int j = 0; j < 8; ++j) {
            float v = ldsx[j * M_ + tid];
            r[j] = __fmul_rn(v, v);
        }
#pragma unroll
        for (int i = 1; i < 8; ++i)
#pragma unroll
            for (int j = 0; j < 8; ++j) {
                float v = ldsx[(i * 8 + j) * M_ + tid];
                r[j] = __fadd_rn(r[j], __fmul_rn(v, v));
            }
        sxs[tid] = __fadd_rn(__fadd_rn(__fadd_rn(r[0], r[1]), __fadd_rn(r[2], r[3])),
                             __fadd_rn(__fadd_rn(r[4], r[5]), __fadd_rn(r[6], r[7])));
    }
    __syncthreads();

    float sxp[8];
#pragma unroll
    for (int pp = 0; pp < 8; ++pp) sxp[pp] = sxs[pg * 8 + pp];

    float runv[8];
    int   runi[8];
#pragma unroll
    for (int pp = 0; pp < 8; ++pp) { runv[pp] = 3.4e38f; runi[pp] = 0; }

    for (int c = 0; c < NCH_; ++c) {
        __syncthreads();                // protect ldse
        // ---- stage embT[d][k] for this code chunk (transpose) ----
#pragma unroll
        for (int i = 0; i < 8; ++i) {
            int q  = i * 256 + tid;     // 0..2047 = 16 dquads * 128 k
            int kl = q & 127;
            int dq = q >> 7;
            float4 v = *(const float4*)(emb + (c * CH_ + kl) * D_ + dq * 4);
            ldse[(dq * 4 + 0) * CH_ + kl] = v.x;
            ldse[(dq * 4 + 1) * CH_ + kl] = v.y;
            ldse[(dq * 4 + 2) * CH_ + kl] = v.z;
            ldse[(dq * 4 + 3) * CH_ + kl] = v.w;
        }
        float4 nh0 = *(const float4*)(wsn + c * CH_ + kg * 8);
        float4 nh1 = *(const float4*)(wsn + c * CH_ + kg * 8 + 4);
        __syncthreads();

        float acc[8][8];
#pragma unroll
        for (int pp = 0; pp < 8; ++pp)
#pragma unroll
            for (int kk = 0; kk < 8; ++kk) acc[pp][kk] = 0.f;

#pragma unroll 2
        for (int d = 0; d < D_; ++d) {
            float4 xa = *(const float4*)(ldsx + d * M_ + pg * 8);
            float4 xb = *(const float4*)(ldsx + d * M_ + pg * 8 + 4);
            float4 ea = *(const float4*)(ldse + d * CH_ + kg * 8);
            float4 eb = *(const float4*)(ldse + d * CH_ + kg * 8 + 4);
            float xr[8] = {xa.x, xa.y, xa.z, xa.w, xb.x, xb.y, xb.z, xb.w};
            float er[8] = {ea.x, ea.y, ea.z, ea.w, eb.x, eb.y, eb.z, eb.w};
#pragma unroll
            for (int pp = 0; pp < 8; ++pp)
#pragma unroll
                for (int kk = 0; kk < 8; ++kk)
                    acc[pp][kk] = fmaf(xr[pp], er[kk], acc[pp][kk]);
        }

        // ---- dist = fp32(fp32(sx + n_k) - 2*dot), argmin, strict < keeps first ----
        float nk[8] = {nh0.x, nh0.y, nh0.z, nh0.w, nh1.x, nh1.y, nh1.z, nh1.w};
#pragma unroll
        for (int pp = 0; pp < 8; ++pp) {
            float sx = sxp[pp];
#pragma unroll
            for (int kk = 0; kk < 8; ++kk) {
                float t1 = __fadd_rn(sx, nk[kk]);
                float v  = __fadd_rn(t1, -2.0f * acc[pp][kk]);  // 2*dot exact
                if (v < runv[pp]) { runv[pp] = v; runi[pp] = c * CH_ + kg * 8 + kk; }
            }
        }
    }

    // ---- cross-thread argmin per point (tie -> smaller index, matches argmin) ----
    __syncthreads();
    float* sv = ldse;                       // [16][128]
    int*   si = (int*)(ldse + 2048);        // [16][128]
    int*   fi = (int*)(ldse + 4096);        // [128]
#pragma unroll
    for (int pp = 0; pp < 8; ++pp) {
        sv[kg * M_ + pg * 8 + pp] = runv[pp];
        si[kg * M_ + pg * 8 + pp] = runi[pp];
    }
    __syncthreads();
    if (tid < M_) {
        float bv = 3.4e38f; int bi = 0x7fffffff;
#pragma unroll
        for (int g = 0; g < 16; ++g) {
            float v  = sv[g * M_ + tid];
            int   ii = si[g * M_ + tid];
            if (v < bv || (v == bv && ii < bi)) { bv = v; bi = ii; }
        }
        fi[tid] = bi;
        out[1 + NDTOT + n0 + tid] = (float)bi;   // idx as float
    }
    __syncthreads();

    // ---- quantized output (NCHW) + loss partial ----
    float* obase = out + 1 + b * (D_ * HW_) + hw0;
    float local = 0.f;
    for (int i = 0; i < 32; ++i) {
        int q = i * 256 + tid;              // 0..8191 = 64 d * 128 p
        int d = q >> 7;
        int p = q & 127;
        int idx = fi[p];
        float e  = emb[idx * D_ + d];
        float xv = ldsx[d * M_ + p];
        float df = e - xv;
        local = fmaf(df, df, local);
        obase[d * HW_ + p] = e;
    }
#pragma unroll
    for (int off = 32; off > 0; off >>= 1)
        local += __shfl_down(local, off, 64);
    if ((tid & 63) == 0) partial[tid >> 6] = local;
    __syncthreads();
    if (tid == 0) {
        float t = partial[0] + partial[1] + partial[2] + partial[3];
        atomicAdd(out, t * (1.25f / (float)NDTOT));   // loss = 1.25 * mean((q-x)^2)
    }
}

extern "C" void kernel_launch(void* const* d_in, const int* in_sizes, int n_in,
                              void* d_out, int out_size, void* d_ws, size_t ws_size,
                              hipStream_t stream) {
    const float* inp = (const float*)d_in[0];
    const float* emb = (const float*)d_in[1];
    float* out = (float*)d_out;
    float* wsn = (float*)d_ws;      // 512 floats: ||e_k||^2

    hipMemsetAsync(d_out, 0, sizeof(float), stream);   // loss accumulator
    vq_norm_kernel<<<2, 256, 0, stream>>>(emb, wsn);
    vq_main_kernel<<<512, 256, 0, stream>>>(inp, emb, wsn, out);
}